// Round 8
// baseline (512.882 us; speedup 1.0000x reference)
//
#include <hip/hip_runtime.h>
#include <hip/hip_bf16.h>
#include <stdint.h>

typedef unsigned short u16;
typedef __attribute__((ext_vector_type(8))) short short8;
typedef __attribute__((ext_vector_type(4))) float f32x4;

#define BATCH 4096
#define DIN   1024
#define NH    1024
#define KTOT  2048

__device__ __forceinline__ void gload_lds16(const void* gp, void* lp) {
    __builtin_amdgcn_global_load_lds(
        (const __attribute__((address_space(1))) uint32_t*)gp,
        (__attribute__((address_space(3))) uint32_t*)lp, 16, 0, 0);
}

__device__ __forceinline__ u16 f2bf(float f) {   // round-to-nearest-even
    uint32_t t; __builtin_memcpy(&t, &f, 4);
    uint32_t r = (t + 0x7FFFu + ((t >> 16) & 1u)) >> 16;
    return (u16)r;
}
__device__ __forceinline__ float hsig(float z) {
    return fminf(fmaxf(fmaf(z, 0.2f, 0.5f), 0.0f), 1.0f);
}
__device__ __forceinline__ float fast_tanh(float x) {
    x = fminf(fmaxf(x, -12.0f), 12.0f);
    float e = __expf(2.0f * x);
    return (e - 1.0f) / (e + 1.0f);
}

// ---------------------------------------------------------------------------
// Prep kernel — WEIGHTS ONLY now (activation cast moved into the GEMM).
// 2048 blocks: cast+transpose+concat -> Bt[(g*NH+n)][KTOT].
// ---------------------------------------------------------------------------
#define WT_BLOCKS 2048
__global__ __launch_bounds__(256) void prep_kernel(
    const float* __restrict__ Wf, const float* __restrict__ Wi,
    const float* __restrict__ Wo, const float* __restrict__ Wc,
    const float* __restrict__ Uf, const float* __restrict__ Ui,
    const float* __restrict__ Uo, const float* __restrict__ Uc,
    u16* __restrict__ Bt)
{
    __shared__ u16 tile[64][65];
    const int bid = blockIdx.x;
    const int tid = threadIdx.x;

    const int mz = bid >> 8;
    const float* srcs[8] = {Wf, Wi, Wo, Wc, Uf, Ui, Uo, Uc};
    const float* src = srcs[mz];
    const int g    = mz & 3;
    const int koff = (mz >> 2) << 10;
    const int k0 = ((bid >> 4) & 15) * 64;
    const int n0 = (bid & 15) * 64;

#pragma unroll
    for (int i = 0; i < 4; i++) {
        int idx = i * 256 + tid;
        int kk = idx >> 4, c = idx & 15;
        float4 v = *(const float4*)(src + (size_t)(k0 + kk) * NH + n0 + c * 4);
        u16* dst = &tile[kk][c * 4];
        dst[0] = f2bf(v.x); dst[1] = f2bf(v.y);
        dst[2] = f2bf(v.z); dst[3] = f2bf(v.w);
    }
    __syncthreads();
#pragma unroll
    for (int i = 0; i < 2; i++) {
        int idx = i * 256 + tid;
        int nn = idx >> 3, c = idx & 7;
        union { u16 v[8]; uint4 q; } pk;
#pragma unroll
        for (int j = 0; j < 8; j++) pk.v[j] = tile[c * 8 + j][nn];
        *(uint4*)(Bt + ((size_t)(g * NH + n0 + nn)) * KTOT + koff + k0 + c * 8) = pk.q;
    }
}

// ---------------------------------------------------------------------------
// R18 GEMM: R17 core (ring-4 BK=32, 8 waves, acc[8][4], reg-dbuf frags,
// full-line epilogue) + A cast in-kernel (Abuf eliminated).
// A staging: per tile, thread (arow=tid>>1, ahalf=tid&1) loads 16 contiguous
// f32 from x (tile<32) or h0 (tile>=32), converts via v_cvt_pk_bf16_f32
// (RNE == f2bf), ds_write_b128 x2 into As slot with chunk swizzle
// pc = c ^ ((arow>>1)&3) — matches frag-read un-swizzle (quad^((am>>1)&3))
// since frag row base is a multiple of 16.
// Issue order per sub-iter (per-wave, in-order VM queue):
//   writeA(T+2)  <- waits A32(T+2) regs => drains VM queue through A32(T+2),
//                   which was issued AFTER stageB(T+2) and AFTER B(T+1)
//                   => B(T+1) landed, pre-barrier => safe for all waves'
//                   loadFrags(T+1) next sub-iter.       [B-land guarantee]
//   stageB(T+3); issueA32(T+3)   (stageB BEFORE issueA32 keeps the above)
//   loadFrags(T+1); mfma(T)
//   lgkmcnt(0)+sched_barrier     <- writer-side drain of A ds_writes
//   s_barrier
// A ds_writes(T+2) are read at T+2, >=2 barriers later; ring-4 slot (T+2)&3
// last read at T-2.  vmcnt never force-drained in-loop (only prologue).
// ---------------------------------------------------------------------------
#define BM   256
#define BNG  64
#define BK   32
#define NT   (KTOT / BK)        // 64
#define TILE_ELEMS (BM * BK)    // 8192 u16 = 16 KB
#define HN_ELEMS ((size_t)BATCH * NH)

__global__ __launch_bounds__(512, 2) void lstm_gemm_kernel(
    const float* __restrict__ x, const float* __restrict__ h0,
    const float* __restrict__ c0, const u16* __restrict__ Bt,
    const float* __restrict__ bfv, const float* __restrict__ biv,
    const float* __restrict__ bov, const float* __restrict__ bcv,
    float* __restrict__ out)
{
    extern __shared__ u16 smem[];            // 128 KiB dynamic LDS
    u16* As = smem;                          // [4][256][32]
    u16* Bs = smem + 4 * TILE_ELEMS;         // [4][256][32] rows = g*64+n

    const int tid  = threadIdx.x;
    const int wv   = tid >> 6;
    const int lane = tid & 63;
    const int wm = wv >> 2;
    const int wn = wv & 3;
    const int m0 = blockIdx.x * BM;
    const int n0 = blockIdx.y * BNG;

    // ---- A staging constants (reg-stage + cvt + ds_write) ----
    const int arow  = tid >> 1;                        // 0..255
    const int ahalf = tid & 1;                         // k-half (16 floats)
    const int akey  = (arow >> 1) & 3;
    const int apc0  = ((ahalf * 2) ^ akey) * 8;        // phys chunk (u16)
    const int apc1  = ((ahalf * 2 + 1) ^ akey) * 8;
    const float* xrow  = x  + (size_t)(m0 + arow) * DIN + ahalf * 16;
    const float* hrow  = h0 + (size_t)(m0 + arow) * DIN + ahalf * 16;

    // ---- B staging constants (unchanged R17) ----
    const int si = wv * 2;
    const int sr = lane >> 2;
    const int kc = (((lane & 3) ^ ((lane >> 3) & 3)) << 3);
    const int rB0 = si * 16 + sr, rB1 = rB0 + 16;      // rows 0..255 = g*64+n
    const u16* bS0 = Bt + (size_t)((rB0 >> 6) * NH + n0 + (rB0 & 63)) * KTOT + kc;
    const u16* bS1 = Bt + (size_t)((rB1 >> 6) * NH + n0 + (rB1 & 63)) * KTOT + kc;
    const int ldsB0 = si * 512, ldsB1 = ldsB0 + 512;

    // ---- fragment constants (unchanged R17) ----
    const int am   = lane & 15;
    const int quad = lane >> 4;
    const int pchunk = ((quad ^ ((am >> 1) & 3)) << 3);
    int aOff[8], bOff[4];
#pragma unroll
    for (int mt = 0; mt < 8; mt++)
        aOff[mt] = (wm * 128 + mt * 16 + am) * BK + pchunk;
#pragma unroll
    for (int g = 0; g < 4; g++)
        bOff[g] = (g * 64 + wn * 16 + am) * BK + pchunk;

    f32x4 acc[8][4];
#pragma unroll
    for (int mt = 0; mt < 8; mt++)
#pragma unroll
        for (int g = 0; g < 4; g++)
            acc[mt][g] = (f32x4){0.f, 0.f, 0.f, 0.f};

    auto issueA32 = [&](int tt, float4 (&fr)[4]) {
        const float* s = (tt < 32) ? (xrow + tt * BK) : (hrow + (tt - 32) * BK);
#pragma unroll
        for (int i = 0; i < 4; i++) fr[i] = ((const float4*)s)[i];
    };
    auto writeA = [&](int tt, float4 (&fr)[4]) {
        u16* dst = As + (tt & 3) * TILE_ELEMS + arow * BK;
        uint32_t w[8];
        const float* f = (const float*)fr;
#pragma unroll
        for (int i = 0; i < 8; i++)
            asm("v_cvt_pk_bf16_f32 %0, %1, %2"
                : "=v"(w[i]) : "v"(f[2 * i]), "v"(f[2 * i + 1]));
        *(uint4*)(dst + apc0) = make_uint4(w[0], w[1], w[2], w[3]);
        *(uint4*)(dst + apc1) = make_uint4(w[4], w[5], w[6], w[7]);
    };
    auto stageB = [&](int S) {
        u16* bd = Bs + (S & 3) * TILE_ELEMS;
        const size_t ko = (size_t)S * BK;
        gload_lds16(bS0 + ko, bd + ldsB0);
        gload_lds16(bS1 + ko, bd + ldsB1);
    };
    auto loadFrags = [&](int t, short8 (&fa)[8], short8 (&fb)[4]) {
        const u16* as = As + (t & 3) * TILE_ELEMS;
        const u16* bs = Bs + (t & 3) * TILE_ELEMS;
#pragma unroll
        for (int mt = 0; mt < 8; mt++)
            fa[mt] = *(const short8*)(as + aOff[mt]);
#pragma unroll
        for (int g = 0; g < 4; g++)
            fb[g] = *(const short8*)(bs + bOff[g]);
    };
    auto mfmaStep = [&](short8 (&fa)[8], short8 (&fb)[4]) {
        __builtin_amdgcn_s_setprio(1);
#pragma unroll
        for (int g = 0; g < 4; g++)
#pragma unroll
            for (int mt = 0; mt < 8; mt++)
                acc[mt][g] = __builtin_amdgcn_mfma_f32_16x16x32_bf16(
                    fa[mt], fb[g], acc[mt][g], 0, 0, 0);
        __builtin_amdgcn_s_setprio(0);
    };

    short8 fA0[8], fB0[4], fA1[8], fB1[4];
    float4 fsP[4], fsQ[4];

    // ---- prologue: A(0),A(1) written; B(0),B(1) landed; A32(2)->Q ----
    issueA32(0, fsP); writeA(0, fsP);
    issueA32(1, fsP); writeA(1, fsP);
    stageB(0); stageB(1); stageB(2);
    issueA32(2, fsQ);
    asm volatile("s_waitcnt vmcnt(6)");      // drains B(0),B(1); leaves B(2)+A32(2)
    asm volatile("s_waitcnt lgkmcnt(0)");
    __builtin_amdgcn_sched_barrier(0);
    __builtin_amdgcn_s_barrier();
    loadFrags(0, fA0, fB0);

    for (int T = 0; T < NT; T += 2) {
        // even sub-iter: tile T
        if (T + 2 < NT) writeA(T + 2, fsQ);
        if (T + 3 < NT) { stageB(T + 3); issueA32(T + 3, fsP); }
        loadFrags(T + 1, fA1, fB1);
        mfmaStep(fA0, fB0);
        asm volatile("s_waitcnt lgkmcnt(0)");
        __builtin_amdgcn_sched_barrier(0);
        __builtin_amdgcn_s_barrier();

        // odd sub-iter: tile T+1
        if (T + 3 < NT) writeA(T + 3, fsP);
        if (T + 4 < NT) { stageB(T + 4); issueA32(T + 4, fsQ); }
        if (T + 2 < NT) loadFrags(T + 2, fA0, fB0);
        mfmaStep(fA1, fB1);
        asm volatile("s_waitcnt lgkmcnt(0)");
        __builtin_amdgcn_sched_barrier(0);
        __builtin_amdgcn_s_barrier();
    }

    // ================= full-line epilogue (R17, unchanged) =================
    const int colE = n0 + wn * 16 + am;
    const float bb0 = bfv[colE], bb1 = biv[colE], bb2 = bov[colE], bb3 = bcv[colE];
    float* zb = (float*)smem;                // [4][128][64] f32 = 128 KB

#pragma unroll 1
    for (int h = 0; h < 2; h++) {
        __syncthreads();
        if (wm == h) {
            const int pc = (wn * 16 + am) ^ (quad << 4);
#pragma unroll
            for (int mt = 0; mt < 8; mt++) {
#pragma unroll
                for (int r = 0; r < 4; r++) {
                    const int row = mt * 16 + quad * 4 + r;
                    float* zr = zb + (size_t)row * 64 + pc;
                    zr[0 * 8192] = acc[mt][0][r] + bb0;
                    zr[1 * 8192] = acc[mt][1][r] + bb1;
                    zr[2 * 8192] = acc[mt][2][r] + bb2;
                    zr[3 * 8192] = acc[mt][3][r] + bb3;
                }
            }
        }
        __syncthreads();
#pragma unroll 1
        for (int p = 0; p < 4; p++) {
            const int row = p * 32 + (tid >> 4);
            const int cs  = (tid & 15) * 4;
            const int pcs = cs ^ (((row >> 2) & 3) << 4);
            const float* zr = zb + (size_t)row * 64;
            f32x4 vf = *(const f32x4*)(zr + 0 * 8192 + pcs);
            f32x4 vi = *(const f32x4*)(zr + 1 * 8192 + pcs);
            f32x4 vo = *(const f32x4*)(zr + 2 * 8192 + pcs);
            f32x4 vc = *(const f32x4*)(zr + 3 * 8192 + pcs);
            const int grow = m0 + h * 128 + row;
            const size_t off = (size_t)grow * NH + n0 + cs;
            f32x4 c0v = *(const f32x4*)(c0 + off);
            f32x4 hnv, cnv;
#pragma unroll
            for (int j = 0; j < 4; j++) {
                float fg = hsig(vf[j]), ig = hsig(vi[j]), og = hsig(vo[j]);
                float ct = fast_tanh(vc[j]);
                float cn = fg * c0v[j] + ig * ct;
                float hn = og * fast_tanh(cn);
                cnv[j] = cn; hnv[j] = hn;
            }
            *(f32x4*)(out + off)                = hnv;   // h
            *(f32x4*)(out + HN_ELEMS + off)     = cnv;   // c
            *(f32x4*)(out + 2 * HN_ELEMS + off) = hnv;   // h (duplicate)
        }
    }
}

extern "C" void kernel_launch(void* const* d_in, const int* in_sizes, int n_in,
                              void* d_out, int out_size, void* d_ws, size_t ws_size,
                              hipStream_t stream) {
    const float* x  = (const float*)d_in[0];
    const float* c0 = (const float*)d_in[1];
    const float* h0 = (const float*)d_in[2];
    const float* Wf = (const float*)d_in[3];
    const float* Wi = (const float*)d_in[4];
    const float* Wo = (const float*)d_in[5];
    const float* Wc = (const float*)d_in[6];
    const float* Uf = (const float*)d_in[7];
    const float* Ui = (const float*)d_in[8];
    const float* Uo = (const float*)d_in[9];
    const float* Uc = (const float*)d_in[10];
    const float* bf = (const float*)d_in[11];
    const float* bi = (const float*)d_in[12];
    const float* bo = (const float*)d_in[13];
    const float* bc = (const float*)d_in[14];

    u16* Bt = (u16*)d_ws;                    // 4 x 1024 x 2048 bf16 = 16 MB

    static bool attr_done = false;
    if (!attr_done) {
        (void)hipFuncSetAttribute((const void*)lstm_gemm_kernel,
                                  hipFuncAttributeMaxDynamicSharedMemorySize,
                                  131072);
        attr_done = true;
    }

    prep_kernel<<<WT_BLOCKS, 256, 0, stream>>>(
        Wf, Wi, Wo, Wc, Uf, Ui, Uo, Uc, Bt);

    dim3 gg(BATCH / BM, NH / BNG);   // 16 x 16 = 256 blocks
    lstm_gemm_kernel<<<gg, 512, 131072, stream>>>(
        x, h0, c0, Bt, bf, bi, bo, bc, (float*)d_out);
}